// Round 6
// baseline (136.654 us; speedup 1.0000x reference)
//
#include <hip/hip_runtime.h>

// Joint bilateral filter 5x5, SAME zero padding.
// template: (1,3,1080,1920) f32 planar; vector: (1,2,1080,1920) f32 planar.
// out: (1,2,1080,1920) f32.
//
// Round 9: break the stage->wait->barrier->compute convoy.
//  Evidence (r3/r8): no pipe >30% busy, ~60% of time idle; bank-conflict
//  cycles are an inherent b128 tax (removing b32 center loads didn't move
//  them). So: 4 tiles per block (64x16 each), double-buffered LDS. Global
//  loads for tile t+1 issue BEFORE the barrier of tile t; their ds_write
//  lands AFTER compute -> HBM latency hides under compute (T14).
//  One barrier per tile. Grid 30x17 = 510 blocks ~= 2/CU, one dispatch wave.
//  Ordering: writes to buf[other] occur after the barrier that follows the
//  last read of buf[other] (prev iteration's compute) -> no extra barrier.
//  Code-shape rules (r4/r7 scratch lessons): no min-waves launch bound, no
//  lambdas, arrays constant-indexed only.

#define IMG_H 1080
#define IMG_W 1920
#define IMG_HW (IMG_H * IMG_W)
#define TS_X 64
#define TS_Y 16
#define NTILE 4                      // tiles per block (64 rows)
#define HALO_H 20                    // TS_Y + 4
#define HALO_W 72                    // TS_X + 8
#define NCH 5
#define F4_PER_ROW 18                // 72/4
#define F4_PER_CH (F4_PER_ROW * HALO_H)   // 360

typedef float f4u __attribute__((ext_vector_type(4), aligned(4)));

// ---- staging macros (expanded inline; no private-array captures) ----
#define LOAD_TILE(Y0) do {                                                 \
    const int tl_ = ((Y0) - 2) * IMG_W + (x0 - 2);                         \
    _Pragma("unroll")                                                      \
    for (int ch_ = 0; ch_ < NCH; ++ch_) {                                  \
        const float* __restrict__ src_ =                                   \
            (ch_ < 3) ? (tpl + ch_ * IMG_HW) : (vec + (ch_ - 3) * IMG_HW); \
        v[2 * ch_]     = *(const f4u*)(src_ + tl_ + off0);                 \
        v[2 * ch_ + 1] = *(const f4u*)(src_ + tl_ + off1);                 \
    }                                                                      \
} while (0)

#define WRITE_TILE(BUF) do {                                               \
    _Pragma("unroll")                                                      \
    for (int ch_ = 0; ch_ < NCH; ++ch_) {                                  \
        float4* d0_ = (float4*)&smem[(BUF)][ch_][r0][c0 * 4];              \
        d0_->x = v[2 * ch_].x; d0_->y = v[2 * ch_].y;                      \
        d0_->z = v[2 * ch_].z; d0_->w = v[2 * ch_].w;                      \
        if (p1) {                                                          \
            float4* d1_ = (float4*)&smem[(BUF)][ch_][r1][c1 * 4];          \
            d1_->x = v[2 * ch_ + 1].x; d1_->y = v[2 * ch_ + 1].y;          \
            d1_->z = v[2 * ch_ + 1].z; d1_->w = v[2 * ch_ + 1].w;          \
        }                                                                  \
    }                                                                      \
} while (0)

#define BORDER_STAGE(BUF, Y0) do {                                         \
    _Pragma("unroll")                                                      \
    for (int ch_ = 0; ch_ < NCH; ++ch_) {                                  \
        const float* __restrict__ src_ =                                   \
            (ch_ < 3) ? (tpl + ch_ * IMG_HW) : (vec + (ch_ - 3) * IMG_HW); \
        for (int i_ = tid; i_ < HALO_H * HALO_W; i_ += 256) {              \
            const int r_   = i_ / HALO_W;                                  \
            const int col_ = i_ - r_ * HALO_W;                             \
            const int gy_  = (Y0) + r_ - 2;                                \
            const int gx_  = x0 + col_ - 2;                                \
            float val_ = 0.0f;                                             \
            if (gy_ >= 0 && gy_ < IMG_H && gx_ >= 0 && gx_ < IMG_W)        \
                val_ = src_[gy_ * IMG_W + gx_];                            \
            smem[(BUF)][ch_][r_][col_] = val_;                             \
        }                                                                  \
    }                                                                      \
} while (0)

__global__ __launch_bounds__(256)
void jbf_kernel(const float* __restrict__ tpl,
                const float* __restrict__ vec,
                float* __restrict__ out) {
    constexpr float SIDIV = 50.0f;   // 1/(2*sigma_intensity^2)
    // coeff = clip(1 - |(-0.125) - id*50|, 0, 1) = max(0.875 - 50*id, 0), id >= 0

    __shared__ __align__(16) float smem[2][NCH][HALO_H][HALO_W];  // 56.25 KB

    const int tid = threadIdx.x;
    const int bx  = blockIdx.x;
    const int x0  = bx * TS_X;
    const int yb  = blockIdx.y * (TS_Y * NTILE);
    const bool xin = (bx >= 1) & (bx <= 28);

    // staging index map (tile-invariant): flat f4 idx -> (row, col4)
    const int i1  = tid + 256;
    const bool p1 = (i1 < F4_PER_CH);            // tid < 104
    const int i1c = p1 ? i1 : 0;
    const int r0 = tid / F4_PER_ROW, c0 = tid - r0 * F4_PER_ROW;
    const int r1 = i1c / F4_PER_ROW, c1 = i1c - r1 * F4_PER_ROW;
    const int off0 = r0 * IMG_W + c0 * 4;
    const int off1 = r1 * IMG_W + c1 * 4;

    // compute index map
    const int tx = tid & 15;
    const int ty = tid >> 4;
    const int lx = tx * 4;         // first owned pixel at halo col lx+2

    f4u v[10];

    // ---- prologue: stage tile 0 into buf 0 ----
    {
        const int y0 = yb;
        if (xin & (y0 >= 2) & (y0 + 17 < IMG_H)) {
            LOAD_TILE(y0);
            WRITE_TILE(0);
        } else {
            BORDER_STAGE(0, y0);
        }
    }

    for (int t = 0; t < NTILE; ++t) {
        const int cur = t & 1;
        const int y0  = yb + t * TS_Y;
        const int yn  = y0 + TS_Y;
        const bool have_next = (t + 1 < NTILE);
        const bool int_next  = have_next && xin && (yn + 17 < IMG_H);

        if (int_next) LOAD_TILE(yn);   // issue early: latency hides under compute
        __syncthreads();               // buf[cur] staging visible to all waves

        // ---- compute tile t from smem[cur] (round-8 verified body) ----
        {
            const float (*S)[HALO_H][HALO_W] =
                (const float (*)[HALO_H][HALO_W])smem[cur];

            float num0[4] = {0.f, 0.f, 0.f, 0.f};
            float num1[4] = {0.f, 0.f, 0.f, 0.f};
            float den [4] = {0.f, 0.f, 0.f, 0.f};
            float cc0[4], cc1[4], cc2[4];

#pragma unroll
            for (int s = 0; s < 5; ++s) {
                constexpr int DYS[5] = {2, 0, 1, 3, 4};
                const int row = ty + DYS[s];
                const float4 a0  = *(const float4*)&S[0][row][lx];
                const float4 b0  = *(const float4*)&S[0][row][lx + 4];
                const float4 a1  = *(const float4*)&S[1][row][lx];
                const float4 b1  = *(const float4*)&S[1][row][lx + 4];
                const float4 a2  = *(const float4*)&S[2][row][lx];
                const float4 b2  = *(const float4*)&S[2][row][lx + 4];
                const float4 av0 = *(const float4*)&S[3][row][lx];
                const float4 bv0 = *(const float4*)&S[3][row][lx + 4];
                const float4 av1 = *(const float4*)&S[4][row][lx];
                const float4 bv1 = *(const float4*)&S[4][row][lx + 4];

                if (s == 0) {   // dy == 2: centers at halo cols lx+2..lx+5
                    cc0[0] = a0.z; cc0[1] = a0.w; cc0[2] = b0.x; cc0[3] = b0.y;
                    cc1[0] = a1.z; cc1[1] = a1.w; cc1[2] = b1.x; cc1[3] = b1.y;
                    cc2[0] = a2.z; cc2[1] = a2.w; cc2[2] = b2.x; cc2[3] = b2.y;
                }

                const float w0[8]  = {a0.x, a0.y, a0.z, a0.w, b0.x, b0.y, b0.z, b0.w};
                const float w1[8]  = {a1.x, a1.y, a1.z, a1.w, b1.x, b1.y, b1.z, b1.w};
                const float w2[8]  = {a2.x, a2.y, a2.z, a2.w, b2.x, b2.y, b2.z, b2.w};
                const float wv0[8] = {av0.x, av0.y, av0.z, av0.w, bv0.x, bv0.y, bv0.z, bv0.w};
                const float wv1[8] = {av1.x, av1.y, av1.z, av1.w, bv1.x, bv1.y, bv1.z, bv1.w};

#pragma unroll
                for (int dx = 0; dx < 5; ++dx) {
#pragma unroll
                    for (int px = 0; px < 4; ++px) {
                        const int k = dx + px;           // halo col lx+k
                        const float d0 = cc0[px] - w0[k];
                        const float d1 = cc1[px] - w1[k];
                        const float d2 = cc2[px] - w2[k];
                        const float id = fmaf(d0, d0, fmaf(d1, d1, d2 * d2));
                        const float coeff = fmaxf(fmaf(id, -SIDIV, 0.875f), 0.0f);
                        num0[px] = fmaf(wv0[k], coeff, num0[px]);
                        num1[px] = fmaf(wv1[k], coeff, num1[px]);
                        den [px] += coeff;
                    }
                }
            }

            const int gy = y0 + ty;
            if (gy < IMG_H) {
                const int gx = x0 + lx;
                float4 o0, o1;
                const float q0 = __builtin_amdgcn_rcpf(den[0]);
                const float q1 = __builtin_amdgcn_rcpf(den[1]);
                const float q2 = __builtin_amdgcn_rcpf(den[2]);
                const float q3 = __builtin_amdgcn_rcpf(den[3]);
                o0.x = num0[0] * q0; o0.y = num0[1] * q1;
                o0.z = num0[2] * q2; o0.w = num0[3] * q3;
                o1.x = num1[0] * q0; o1.y = num1[1] * q1;
                o1.z = num1[2] * q2; o1.w = num1[3] * q3;
                *(float4*)(out + (size_t)0 * IMG_HW + gy * IMG_W + gx) = o0;
                *(float4*)(out + (size_t)1 * IMG_HW + gy * IMG_W + gx) = o1;
            }
        }

        // ---- stage tile t+1 into the other buffer (write-late) ----
        if (have_next) {
            if (int_next) {
                WRITE_TILE(1 - cur);
            } else {
                BORDER_STAGE(1 - cur, yn);
            }
        }
    }
}

extern "C" void kernel_launch(void* const* d_in, const int* in_sizes, int n_in,
                              void* d_out, int out_size, void* d_ws, size_t ws_size,
                              hipStream_t stream) {
    const float* tpl = (const float*)d_in[0];
    const float* vec = (const float*)d_in[1];
    float* out = (float*)d_out;

    dim3 grid(IMG_W / TS_X, (IMG_H + TS_Y * NTILE - 1) / (TS_Y * NTILE));  // 30 x 17
    jbf_kernel<<<grid, 256, 0, stream>>>(tpl, vec, out);
}

// Round 7
// 126.362 us; speedup vs baseline: 1.0815x; 1.0815x over previous
//
#include <hip/hip_runtime.h>

// Joint bilateral filter 5x5, SAME zero padding.
// template: (1,3,1080,1920) f32 planar; vector: (1,2,1080,1920) f32 planar.
// out: (1,2,1080,1920) f32.
//
// Round 10: round-8 structure (one-shot 64x16 blocks, 2040 blocks, max TLP)
// with ONE change: kill the structural 4-way LDS phase conflict.
//  Analysis: with row stride = 72 or 76 dwords (both = 0 mod 4), all 4
//  row-groups of a wave span the SAME 16-bank residue class on every b128
//  window read -> 64 lanes on 16 banks = 4-way conflict (measured +10.6
//  cyc/instr; unchanged by padding or removing b32s). 16B row alignment
//  makes this inescapable for b128. Fix: stride 74 dwords (= 2 mod 4,
//  rows 8B-aligned) + ALL window reads as ds_read_b64 -> row-groups split
//  across both 16-bank halves = 2-way = free (m136).
//  Staging writes become 2x ds_write_b64 (rows not 16B-aligned).
// Closed directions (measured): 2 rows/thread -> scratch (r4/r7);
// global_load_lds -> wrong results (r5/r6); fewer-blocks dbuf -> TLP
// collapse, 72 us (r9).

#define IMG_H 1080
#define IMG_W 1920
#define IMG_HW (IMG_H * IMG_W)
#define TS_X 64      // tile width  (pixels)
#define TS_Y 16      // tile height (pixels)
#define HALO_H 20    // TS_Y + 4
#define HALO_W 72    // data columns: image cols x0-2 .. x0+69 (18 f4/row)
#define LDS_W 74     // row stride in dwords: 74 mod 32 = 10 (== 2 mod 4)
#define NCH 5
#define F4_PER_ROW 18            // 72/4
#define F4_PER_CH  (F4_PER_ROW * HALO_H)   // 360

typedef float f4u __attribute__((ext_vector_type(4), aligned(4)));

__global__ __launch_bounds__(256)
void jbf_kernel(const float* __restrict__ tpl,
                const float* __restrict__ vec,
                float* __restrict__ out) {
    constexpr float SIDIV = 50.0f;    // 1/(2*sigma_intensity^2)
    // coeff = clip(1 - |(-0.125) - id*50|, 0, 1) = max(0.875 - 50*id, 0), id >= 0

    __shared__ __align__(16) float smem[NCH][HALO_H][LDS_W];

    const int tid = threadIdx.x;
    const int x0  = blockIdx.x * TS_X;
    const int y0  = blockIdx.y * TS_Y;

    // interior: whole 20x72 halo window in-bounds (no zero padding needed)
    const bool interior = (blockIdx.x >= 1) & (blockIdx.x <= 28) &
                          (blockIdx.y >= 1) & (blockIdx.y <= 66);

    if (interior) {
        // flat f4 index per channel: idx in [0,360); row=idx/18, col4=idx%18
        const int i0  = tid;
        const int i1  = tid + 256;
        const bool p1 = (i1 < F4_PER_CH);          // tid < 104
        const int i1c = p1 ? i1 : 0;
        const int r0 = i0 / F4_PER_ROW, c0 = i0 - r0 * F4_PER_ROW;
        const int r1 = i1c / F4_PER_ROW, c1 = i1c - r1 * F4_PER_ROW;
        const int off0 = r0 * IMG_W + c0 * 4;
        const int off1 = r1 * IMG_W + c1 * 4;
        const int tl   = (y0 - 2) * IMG_W + (x0 - 2);   // top-left of halo

        f4u v[2 * NCH];
#pragma unroll
        for (int ch = 0; ch < NCH; ++ch) {
            const float* __restrict__ src =
                (ch < 3) ? (tpl + ch * IMG_HW) : (vec + (ch - 3) * IMG_HW);
            v[2 * ch]     = *(const f4u*)(src + tl + off0);
            v[2 * ch + 1] = *(const f4u*)(src + tl + off1);
        }
#pragma unroll
        for (int ch = 0; ch < NCH; ++ch) {
            // rows are only 8B-aligned (stride 74): write as 2x float2 (b64)
            float2* d0a = (float2*)&smem[ch][r0][c0 * 4];
            float2* d0b = (float2*)&smem[ch][r0][c0 * 4 + 2];
            d0a->x = v[2 * ch].x; d0a->y = v[2 * ch].y;
            d0b->x = v[2 * ch].z; d0b->y = v[2 * ch].w;
            if (p1) {
                float2* d1a = (float2*)&smem[ch][r1][c1 * 4];
                float2* d1b = (float2*)&smem[ch][r1][c1 * 4 + 2];
                d1a->x = v[2 * ch + 1].x; d1a->y = v[2 * ch + 1].y;
                d1b->x = v[2 * ch + 1].z; d1b->y = v[2 * ch + 1].w;
            }
        }
    } else {
        // border: scalar bounds-checked staging with zero fill
#pragma unroll
        for (int c = 0; c < NCH; ++c) {
            const float* __restrict__ src =
                (c < 3) ? (tpl + c * IMG_HW) : (vec + (c - 3) * IMG_HW);
#pragma unroll
            for (int i = tid; i < HALO_H * HALO_W; i += 256) {
                const int r   = i / HALO_W;
                const int col = i - r * HALO_W;
                const int gy  = y0 + r - 2;
                const int gx  = x0 + col - 2;
                float val = 0.0f;
                if (gy >= 0 && gy < IMG_H && gx >= 0 && gx < IMG_W)
                    val = src[gy * IMG_W + gx];
                smem[c][r][col] = val;
            }
        }
    }
    __syncthreads();

    const int tx = tid & 15;   // 16 threads across
    const int ty = tid >> 4;   // 16 rows
    const int lx = tx * 4;     // first owned pixel at halo col lx+2

    float num0[4] = {0.f, 0.f, 0.f, 0.f};
    float num1[4] = {0.f, 0.f, 0.f, 0.f};
    float den [4] = {0.f, 0.f, 0.f, 0.f};
    float c0[4], c1[4], c2[4];

    // dy order {2,0,1,3,4}: centers come from the dy=2 window reads
    // (center px p = halo col lx+2+p = w[p+2]). Accumulation order-invariant.
#pragma unroll
    for (int s = 0; s < 5; ++s) {
        constexpr int DYS[5] = {2, 0, 1, 3, 4};
        const int row = ty + DYS[s];
        const float* base0 = &smem[0][row][lx];
        const float* base1 = &smem[1][row][lx];
        const float* base2 = &smem[2][row][lx];
        const float* base3 = &smem[3][row][lx];
        const float* base4 = &smem[4][row][lx];

        // 8-float window per channel as 4x float2 (b64, 8B-aligned, 2-way banks)
        const float2 p00 = *(const float2*)(base0 + 0);
        const float2 p01 = *(const float2*)(base0 + 2);
        const float2 p02 = *(const float2*)(base0 + 4);
        const float2 p03 = *(const float2*)(base0 + 6);
        const float2 p10 = *(const float2*)(base1 + 0);
        const float2 p11 = *(const float2*)(base1 + 2);
        const float2 p12 = *(const float2*)(base1 + 4);
        const float2 p13 = *(const float2*)(base1 + 6);
        const float2 p20 = *(const float2*)(base2 + 0);
        const float2 p21 = *(const float2*)(base2 + 2);
        const float2 p22 = *(const float2*)(base2 + 4);
        const float2 p23 = *(const float2*)(base2 + 6);
        const float2 p30 = *(const float2*)(base3 + 0);
        const float2 p31 = *(const float2*)(base3 + 2);
        const float2 p32 = *(const float2*)(base3 + 4);
        const float2 p33 = *(const float2*)(base3 + 6);
        const float2 p40 = *(const float2*)(base4 + 0);
        const float2 p41 = *(const float2*)(base4 + 2);
        const float2 p42 = *(const float2*)(base4 + 4);
        const float2 p43 = *(const float2*)(base4 + 6);

        if (s == 0) {   // dy == 2: centers at halo cols lx+2..lx+5
            c0[0] = p01.x; c0[1] = p01.y; c0[2] = p02.x; c0[3] = p02.y;
            c1[0] = p11.x; c1[1] = p11.y; c1[2] = p12.x; c1[3] = p12.y;
            c2[0] = p21.x; c2[1] = p21.y; c2[2] = p22.x; c2[3] = p22.y;
        }

        const float w0[8]  = {p00.x, p00.y, p01.x, p01.y, p02.x, p02.y, p03.x, p03.y};
        const float w1[8]  = {p10.x, p10.y, p11.x, p11.y, p12.x, p12.y, p13.x, p13.y};
        const float w2[8]  = {p20.x, p20.y, p21.x, p21.y, p22.x, p22.y, p23.x, p23.y};
        const float wv0[8] = {p30.x, p30.y, p31.x, p31.y, p32.x, p32.y, p33.x, p33.y};
        const float wv1[8] = {p40.x, p40.y, p41.x, p41.y, p42.x, p42.y, p43.x, p43.y};

#pragma unroll
        for (int dx = 0; dx < 5; ++dx) {
#pragma unroll
            for (int px = 0; px < 4; ++px) {
                const int k = dx + px;           // halo col lx+k
                const float d0 = c0[px] - w0[k];
                const float d1 = c1[px] - w1[k];
                const float d2 = c2[px] - w2[k];
                const float id = fmaf(d0, d0, fmaf(d1, d1, d2 * d2));
                const float coeff = fmaxf(fmaf(id, -SIDIV, 0.875f), 0.0f);
                num0[px] = fmaf(wv0[k], coeff, num0[px]);
                num1[px] = fmaf(wv1[k], coeff, num1[px]);
                den [px] += coeff;
            }
        }
    }

    const int gy = y0 + ty;
    if (gy < IMG_H) {
        const int gx = x0 + lx;
        float4 o0, o1;
        const float r0 = __builtin_amdgcn_rcpf(den[0]);
        const float r1 = __builtin_amdgcn_rcpf(den[1]);
        const float r2 = __builtin_amdgcn_rcpf(den[2]);
        const float r3 = __builtin_amdgcn_rcpf(den[3]);
        o0.x = num0[0] * r0; o0.y = num0[1] * r1; o0.z = num0[2] * r2; o0.w = num0[3] * r3;
        o1.x = num1[0] * r0; o1.y = num1[1] * r1; o1.z = num1[2] * r2; o1.w = num1[3] * r3;
        *(float4*)(out + (size_t)0 * IMG_HW + gy * IMG_W + gx) = o0;
        *(float4*)(out + (size_t)1 * IMG_HW + gy * IMG_W + gx) = o1;
    }
}

extern "C" void kernel_launch(void* const* d_in, const int* in_sizes, int n_in,
                              void* d_out, int out_size, void* d_ws, size_t ws_size,
                              hipStream_t stream) {
    const float* tpl = (const float*)d_in[0];
    const float* vec = (const float*)d_in[1];
    float* out = (float*)d_out;

    dim3 grid(IMG_W / TS_X, (IMG_H + TS_Y - 1) / TS_Y);  // 30 x 68
    jbf_kernel<<<grid, 256, 0, stream>>>(tpl, vec, out);
}

// Round 8
// 117.865 us; speedup vs baseline: 1.1594x; 1.0721x over previous
//
#include <hip/hip_runtime.h>

// Joint bilateral filter 5x5, SAME zero padding.
// template: (1,3,1080,1920) f32 planar; vector: (1,2,1080,1920) f32 planar.
// out: (1,2,1080,1920) f32.
//
// Round 11: NO LDS. Evidence across r3/r8/r9/r10: latency-bound, dur tracks
// occupancy only; the stage->vmcnt->ds_write->barrier->ds_read chain plus
// LDS residency is pure overhead for a 5x5 window whose per-block footprint
// (28KB) is L1-resident anyway, with only ~5x reuse. Each thread loads its
// 5ch x 8-float row window directly from global (10 coalesced dwordx4 per
// dy): adjacent threads cover contiguous 16B, the block halo fits L1 after
// first touch, and with zero barriers the waves are fully independent ->
// TLP finally hides latency. Rolled dy loop (#pragma unroll 1) caps VGPR
// below the 128 occupancy cliff (r10 lesson). Tap math and center
// extraction (dy=2 row, w[p+2]) verified in r8's passing run.

#define IMG_H 1080
#define IMG_W 1920
#define IMG_HW (IMG_H * IMG_W)
#define TS_X 64
#define TS_Y 16

typedef float f4u __attribute__((ext_vector_type(4), aligned(4)));

#define UNPACK8(dst, A, B) \
    dst[0]=(A).x; dst[1]=(A).y; dst[2]=(A).z; dst[3]=(A).w; \
    dst[4]=(B).x; dst[5]=(B).y; dst[6]=(B).z; dst[7]=(B).w;

// interior: row guaranteed in [0,H), cols gx-2..gx+5 in [0,W)
#define LOAD_FAST(ROW) do {                                                   \
    const float* p_ = tpl + (ROW) * IMG_W + (gx - 2);                         \
    const float* q_ = vec + (ROW) * IMG_W + (gx - 2);                         \
    const f4u a0_  = *(const f4u*)(p_);                                       \
    const f4u b0_  = *(const f4u*)(p_ + 4);                                   \
    const f4u a1_  = *(const f4u*)(p_ + IMG_HW);                              \
    const f4u b1_  = *(const f4u*)(p_ + IMG_HW + 4);                          \
    const f4u a2_  = *(const f4u*)(p_ + 2 * IMG_HW);                          \
    const f4u b2_  = *(const f4u*)(p_ + 2 * IMG_HW + 4);                      \
    const f4u av0_ = *(const f4u*)(q_);                                       \
    const f4u bv0_ = *(const f4u*)(q_ + 4);                                   \
    const f4u av1_ = *(const f4u*)(q_ + IMG_HW);                              \
    const f4u bv1_ = *(const f4u*)(q_ + IMG_HW + 4);                          \
    UNPACK8(w0,  a0_,  b0_)  UNPACK8(w1,  a1_,  b1_)                          \
    UNPACK8(w2,  a2_,  b2_)  UNPACK8(wv0, av0_, bv0_)                         \
    UNPACK8(wv1, av1_, bv1_)                                                  \
} while (0)

// y-border, x-interior: columns safe, row clamped + zero mask
#define LOAD_CLAMPY(ROW) do {                                                 \
    const int   rc_ = (ROW) < 0 ? 0 : ((ROW) > IMG_H - 1 ? IMG_H - 1 : (ROW));\
    const float m_  = ((ROW) >= 0 && (ROW) < IMG_H) ? 1.0f : 0.0f;            \
    LOAD_FAST(rc_);                                                           \
    _Pragma("unroll")                                                         \
    for (int k_ = 0; k_ < 8; ++k_) {                                          \
        w0[k_] *= m_; w1[k_] *= m_; w2[k_] *= m_;                             \
        wv0[k_] *= m_; wv1[k_] *= m_;                                         \
    }                                                                         \
} while (0)

// x-border: per-element clamp + zero mask (rare: bx in {0,29})
#define LOAD_SLOW(ROW) do {                                                   \
    const bool rv_ = ((ROW) >= 0) & ((ROW) < IMG_H);                          \
    const int  rb_ = (rv_ ? (ROW) : 0) * IMG_W;                               \
    _Pragma("unroll")                                                         \
    for (int k_ = 0; k_ < 8; ++k_) {                                          \
        const int   col_ = gx - 2 + k_;                                       \
        const bool  v_   = rv_ & (col_ >= 0) & (col_ < IMG_W);                \
        const int   ic_  = rb_ + (v_ ? col_ : 0);                             \
        const float m_   = v_ ? 1.0f : 0.0f;                                  \
        w0[k_]  = m_ * tpl[ic_];                                              \
        w1[k_]  = m_ * tpl[ic_ + IMG_HW];                                     \
        w2[k_]  = m_ * tpl[ic_ + 2 * IMG_HW];                                 \
        wv0[k_] = m_ * vec[ic_];                                              \
        wv1[k_] = m_ * vec[ic_ + IMG_HW];                                     \
    }                                                                         \
} while (0)

#define LOAD_ROW(ROW) do {                                                    \
    if (xin & yin)  LOAD_FAST(ROW);                                           \
    else if (xin)   LOAD_CLAMPY(ROW);                                         \
    else            LOAD_SLOW(ROW);                                           \
} while (0)

#define TAPS do {                                                             \
    _Pragma("unroll")                                                         \
    for (int dx = 0; dx < 5; ++dx) {                                          \
        _Pragma("unroll")                                                     \
        for (int px = 0; px < 4; ++px) {                                      \
            const int   k  = dx + px;                                         \
            const float d0 = c0[px] - w0[k];                                  \
            const float d1 = c1[px] - w1[k];                                  \
            const float d2 = c2[px] - w2[k];                                  \
            const float id = fmaf(d0, d0, fmaf(d1, d1, d2 * d2));             \
            const float coeff = fmaxf(fmaf(id, -SIDIV, 0.875f), 0.0f);        \
            num0[px] = fmaf(wv0[k], coeff, num0[px]);                         \
            num1[px] = fmaf(wv1[k], coeff, num1[px]);                         \
            den [px] += coeff;                                                \
        }                                                                     \
    }                                                                         \
} while (0)

__global__ __launch_bounds__(256)
void jbf_kernel(const float* __restrict__ tpl,
                const float* __restrict__ vec,
                float* __restrict__ out) {
    constexpr float SIDIV = 50.0f;   // 1/(2*sigma_intensity^2)
    // coeff = clip(1 - |(-0.125) - id*50|, 0, 1) = max(0.875 - 50*id, 0), id >= 0

    const int tid = threadIdx.x;
    const int tx  = tid & 15;              // 16 threads across
    const int ty  = tid >> 4;              // 16 rows
    const int gx  = blockIdx.x * TS_X + tx * 4;   // first owned pixel col
    const int gy  = blockIdx.y * TS_Y + ty;       // owned row

    const bool xin = (blockIdx.x >= 1) & (blockIdx.x <= 28);
    const bool yin = (blockIdx.y >= 1) & (blockIdx.y <= 66);

    float num0[4] = {0.f, 0.f, 0.f, 0.f};
    float num1[4] = {0.f, 0.f, 0.f, 0.f};
    float den [4] = {0.f, 0.f, 0.f, 0.f};
    float c0[4], c1[4], c2[4];
    float w0[8], w1[8], w2[8], wv0[8], wv1[8];

    // center row first (dy = 2): extract centers, then its taps.
    // window cols gx-2 .. gx+5; center px p at col gx+p -> w[p+2].
    LOAD_ROW(gy);
    c0[0] = w0[2]; c0[1] = w0[3]; c0[2] = w0[4]; c0[3] = w0[5];
    c1[0] = w1[2]; c1[1] = w1[3]; c1[2] = w1[4]; c1[3] = w1[5];
    c2[0] = w2[2]; c2[1] = w2[3]; c2[2] = w2[4]; c2[3] = w2[5];
    TAPS;

    // remaining rows dy = {0,1,3,4}; rolled to cap VGPR below the 128 cliff
#pragma unroll 1
    for (int j = 0; j < 4; ++j) {
        const int dy = j + (j >> 1);       // 0,1,3,4
        LOAD_ROW(gy + dy - 2);
        TAPS;
    }

    if (gy < IMG_H) {
        float4 o0, o1;
        const float r0 = __builtin_amdgcn_rcpf(den[0]);
        const float r1 = __builtin_amdgcn_rcpf(den[1]);
        const float r2 = __builtin_amdgcn_rcpf(den[2]);
        const float r3 = __builtin_amdgcn_rcpf(den[3]);
        o0.x = num0[0] * r0; o0.y = num0[1] * r1; o0.z = num0[2] * r2; o0.w = num0[3] * r3;
        o1.x = num1[0] * r0; o1.y = num1[1] * r1; o1.z = num1[2] * r2; o1.w = num1[3] * r3;
        *(float4*)(out + (size_t)0 * IMG_HW + gy * IMG_W + gx) = o0;
        *(float4*)(out + (size_t)1 * IMG_HW + gy * IMG_W + gx) = o1;
    }
}

extern "C" void kernel_launch(void* const* d_in, const int* in_sizes, int n_in,
                              void* d_out, int out_size, void* d_ws, size_t ws_size,
                              hipStream_t stream) {
    const float* tpl = (const float*)d_in[0];
    const float* vec = (const float*)d_in[1];
    float* out = (float*)d_out;

    dim3 grid(IMG_W / TS_X, (IMG_H + TS_Y - 1) / TS_Y);  // 30 x 68
    jbf_kernel<<<grid, 256, 0, stream>>>(tpl, vec, out);
}